// Round 18
// baseline (103.996 us; speedup 1.0000x reference)
//
#include <hip/hip_runtime.h>
#include <math.h>

#define S_LEN 56
#define DH 128

typedef float f32x4 __attribute__((ext_vector_type(4)));
typedef unsigned short u16x8 __attribute__((ext_vector_type(8)));
typedef unsigned short u16x4 __attribute__((ext_vector_type(4)));

__device__ __forceinline__ unsigned short f2bf(float f) {
  unsigned int u = __builtin_bit_cast(unsigned int, f);
  u += 0x7fffu + ((u >> 16) & 1u);  // RNE
  return (unsigned short)(u >> 16);
}
__device__ __forceinline__ unsigned short tobf(float f) {
  __bf16 h = (__bf16)f;
  return __builtin_bit_cast(unsigned short, h);
}
__device__ __forceinline__ u16x4 pk4(f32x4 v) {
  u16x4 r;
  r[0] = tobf(v[0]); r[1] = tobf(v[1]); r[2] = tobf(v[2]); r[3] = tobf(v[3]);
  return r;
}
__device__ __forceinline__ u16x8 pk8(f32x4 a, f32x4 b) {
  u16x8 r;
  r[0] = tobf(a[0]); r[1] = tobf(a[1]); r[2] = tobf(a[2]); r[3] = tobf(a[3]);
  r[4] = tobf(b[0]); r[5] = tobf(b[1]); r[6] = tobf(b[2]); r[7] = tobf(b[3]);
  return r;
}
__device__ __forceinline__ u16x8 cmb(u16x4 lo, u16x4 hi) {
  u16x8 r;
  r[0] = lo[0]; r[1] = lo[1]; r[2] = lo[2]; r[3] = lo[3];
  r[4] = hi[0]; r[5] = hi[1]; r[6] = hi[2]; r[7] = hi[3];
  return r;
}

template <typename V>
__device__ __forceinline__ auto mfma_sel(V a, V b, f32x4 c, int)
    -> decltype(__builtin_amdgcn_mfma_f32_16x16x32_bf16(a, b, c, 0, 0, 0)) {
  return __builtin_amdgcn_mfma_f32_16x16x32_bf16(a, b, c, 0, 0, 0);
}
template <typename V, typename E = __bf16>
__device__ __forceinline__ f32x4 mfma_sel(V a, V b, f32x4 c, long) {
  typedef E bfv __attribute__((ext_vector_type(8)));
  return __builtin_amdgcn_mfma_f32_16x16x32_bf16(
      __builtin_bit_cast(bfv, a), __builtin_bit_cast(bfv, b), c, 0, 0, 0);
}
__device__ __forceinline__ f32x4 MFMA(u16x8 a, u16x8 b, f32x4 c) {
  return mfma_sel(a, b, c, 0);
}

// One prep launch (r17-proven). Slot 0: A^T (A = Wq^T Wk). Slot 1: W2 = Wo·Wv.
__global__ void conv_all(const float* __restrict__ wq, const float* __restrict__ wk,
                         const float* __restrict__ wv, const float* __restrict__ wo,
                         unsigned short* __restrict__ o) {
  int bid = blockIdx.x;
  int i = (bid & 63) * 256 + threadIdx.x;  // 0..16383
  int r = i >> 7, c = i & 127;
  float s = 0.f;
  if (bid < 64) {
#pragma unroll 8
    for (int d = 0; d < DH; ++d) s += wq[d * DH + r] * wk[d * DH + c];
    o[c * DH + r] = f2bf(s);               // A^T[c][r] = A[r][c]
  } else {
#pragma unroll 8
    for (int d = 0; d < DH; ++d) s += wo[r * DH + d] * wv[d * DH + c];
    o[DH * DH + r * DH + c] = f2bf(s);     // W2[r][c], row-major
  }
}

// Cooperative 128x128-u16 weight stage: exactly 8 chunks = 32 KB (r13-fixed).
__device__ __forceinline__ void stageW(const unsigned short* __restrict__ src,
                                       unsigned short* wsh, int tid) {
  u16x8 v[8];
#pragma unroll
  for (int j = 0; j < 8; ++j)
    v[j] = *(const u16x8*)(src + ((j * 256 + tid) << 3));
#pragma unroll
  for (int j = 0; j < 8; ++j) {
    int row = j * 16 + (tid >> 4);
    int g = (tid & 15) ^ (row & 7);
    *(u16x8*)((char*)wsh + (row << 8) + (g << 4)) = v[j];
  }
}

// pi-fragment read from the swizzled LDS weight tile (r11-proven).
__device__ __forceinline__ u16x8 ldw(const unsigned short* wsh, int row,
                                     int kt, int lq) {
  int m = (row & 7) << 4;
  int p = (kt << 3) + lq;                     // 8-byte piece index
  int a0 = (row << 8) + (((p) << 3) ^ m);
  int a1 = (row << 8) + (((p + 4) << 3) ^ m);
  u16x4 lo = *(const u16x4*)((const char*)wsh + a0);
  u16x4 hi = *(const u16x4*)((const char*)wsh + a1);
  return cmb(lo, hi);
}

// r17 math verbatim, liveness-reduced for 3 waves/SIMD:
//  (1) E/softmax split into qt-halves (Ea[4][4] -> Ea[2][4], -32 VGPR);
//  (2) V' -> PV fused per dt-tile (av[8][2] array eliminated, -56 VGPR);
//  (3) single 32 KB LDS buffer (A^T, then W2), 3 barriers.
// Peak liveness ~150-168 -> launch_bounds(256,3): 12 waves/CU (+50%).
__global__ __launch_bounds__(256, 3) void tb_fused(
    const float* __restrict__ xg, const unsigned short* __restrict__ wbf,
    const int* __restrict__ lens, float* __restrict__ outg,
    float* __restrict__ attng) {
  __shared__ __align__(16) unsigned short wsh[DH * DH];  // 32 KB

  const int tid = threadIdx.x;
  const int w = tid >> 6;        // wave id -> sample
  const int lane = tid & 63;
  const int l15 = lane & 15;
  const int lq = lane >> 4;      // 0..3
  const int b = blockIdx.x * 4 + w;

  const int len = lens[b];
  const float* __restrict__ xb = xg + (size_t)b * (S_LEN * DH);

  // ---- stage A^T; x -> afp overlaps staging latency ----
  stageW(wbf, wsh, tid);
  u16x8 afp[4][4];
#pragma unroll
  for (int rt = 0; rt < 4; ++rt) {
    int row = (rt << 4) + l15;
#pragma unroll
    for (int kt = 0; kt < 4; ++kt) {
      u16x8 h = {0, 0, 0, 0, 0, 0, 0, 0};
      if (row < S_LEN) {
        const float* p = xb + row * DH + (kt << 5) + (lq << 2);
        f32x4 lo = *(const f32x4*)p;
        f32x4 hi = *(const f32x4*)(p + 16);
        h = pk8(lo, hi);
      }
      afp[rt][kt] = h;
    }
  }
  __syncthreads();  // B1: A^T staged

  const float sca = 0.08838834764831845f;  // 1/sqrt(128)
  const float slen = sqrtf((float)len);
  float* __restrict__ ab = attng + (size_t)b * (S_LEN * S_LEN);
  u16x8 pp[2][4];  // P'^T fragments, filled per qt-half

  // ---- E + softmax in TWO qt-halves (halved Ea liveness) ----
#pragma unroll
  for (int h = 0; h < 2; ++h) {
    f32x4 Ea[2][4];  // [q2][nt]; q = 16(2h+q2)+l15, k' = 16nt+4lq+r
#pragma unroll
    for (int q2 = 0; q2 < 2; ++q2)
#pragma unroll
      for (int nt = 0; nt < 4; ++nt) Ea[q2][nt] = f32x4{0.f, 0.f, 0.f, 0.f};

#pragma unroll
    for (int jp = 0; jp < 4; ++jp) {
      const int t0 = jp << 1, t1 = (jp << 1) | 1;
      u16x8 wf0[4], wf1[4];
#pragma unroll
      for (int kt = 0; kt < 4; ++kt) {
        wf0[kt] = ldw(wsh, (t0 << 4) + l15, kt, lq);
        wf1[kt] = ldw(wsh, (t1 << 4) + l15, kt, lq);
      }
      __builtin_amdgcn_s_setprio(1);
      f32x4 ya0[2], ya1[2];
#pragma unroll
      for (int q2 = 0; q2 < 2; ++q2) {
        ya0[q2] = f32x4{0.f, 0.f, 0.f, 0.f};
        ya1[q2] = f32x4{0.f, 0.f, 0.f, 0.f};
      }
#pragma unroll
      for (int kt = 0; kt < 4; ++kt)
#pragma unroll
        for (int q2 = 0; q2 < 2; ++q2) {
          ya0[q2] = MFMA(wf0[kt], afp[(h << 1) + q2][kt], ya0[q2]);
          ya1[q2] = MFMA(wf1[kt], afp[(h << 1) + q2][kt], ya1[q2]);
        }
      u16x8 yp[2];
#pragma unroll
      for (int q2 = 0; q2 < 2; ++q2) yp[q2] = pk8(ya0[q2], ya1[q2]);
#pragma unroll
      for (int nt = 0; nt < 4; ++nt)
#pragma unroll
        for (int q2 = 0; q2 < 2; ++q2)
          Ea[q2][nt] = MFMA(afp[nt][jp], yp[q2], Ea[q2][nt]);
      __builtin_amdgcn_s_setprio(0);
    }

    // scale, mask, softmax, attn store, pp pack for this half
#pragma unroll
    for (int q2 = 0; q2 < 2; ++q2) {
#pragma unroll
      for (int nt = 0; nt < 4; ++nt)
#pragma unroll
        for (int r = 0; r < 4; ++r) {
          int kk = (nt << 4) + (lq << 2) + r;
          Ea[q2][nt][r] = (kk < len) ? Ea[q2][nt][r] * sca : -1e30f;
        }
      float m = -1e30f;
#pragma unroll
      for (int nt = 0; nt < 4; ++nt)
        m = fmaxf(m, fmaxf(fmaxf(Ea[q2][nt][0], Ea[q2][nt][1]),
                           fmaxf(Ea[q2][nt][2], Ea[q2][nt][3])));
      m = fmaxf(m, __shfl_xor(m, 16, 64));
      m = fmaxf(m, __shfl_xor(m, 32, 64));
      float s = 0.f;
#pragma unroll
      for (int nt = 0; nt < 4; ++nt)
#pragma unroll
        for (int r = 0; r < 4; ++r) {
          float p = __expf(Ea[q2][nt][r] - m);
          Ea[q2][nt][r] = p;
          s += p;
        }
      s += __shfl_xor(s, 16, 64);
      s += __shfl_xor(s, 32, 64);
      float iv = 1.f / s;
      float islen = iv * slen;

      int q = (((h << 1) + q2) << 4) + l15;
#pragma unroll
      for (int nt = 0; nt < 4; ++nt) {
        int cs = (nt << 4) + (lq << 2);
        f32x4 pv = Ea[q2][nt] * iv;
        if (q < S_LEN && cs < S_LEN) *(f32x4*)&ab[q * S_LEN + cs] = pv;
      }
      pp[0][(h << 1) + q2] = pk8(Ea[q2][0] * islen, Ea[q2][1] * islen);
      pp[1][(h << 1) + q2] = pk8(Ea[q2][2] * islen, Ea[q2][3] * islen);
    }
  }

  __syncthreads();                 // B2: all A^T reads done
  stageW(wbf + DH * DH, wsh, tid); // W2 -> LDS
  __syncthreads();                 // B3: W2 staged

  // ---- V' = x@W2^T fused with PV per dt-tile (no av array) ----
  float* __restrict__ ob = outg + (size_t)b * (S_LEN * DH);
#pragma unroll
  for (int dt = 0; dt < 8; ++dt) {
    u16x8 bfr[4];
#pragma unroll
    for (int kt = 0; kt < 4; ++kt)
      bfr[kt] = ldw(wsh, (dt << 4) + l15, kt, lq);
    __builtin_amdgcn_s_setprio(1);
    f32x4 vacc[4];
#pragma unroll
    for (int mt = 0; mt < 4; ++mt) vacc[mt] = f32x4{0.f, 0.f, 0.f, 0.f};
#pragma unroll
    for (int kt = 0; kt < 4; ++kt)
#pragma unroll
      for (int mt = 0; mt < 4; ++mt)
        vacc[mt] = MFMA(afp[mt][kt], bfr[kt], vacc[mt]);
    u16x8 av0 = cmb(pk4(vacc[0]), pk4(vacc[1]));  // s-tiles 0,1 (k' 0..31)
    u16x8 av1 = cmb(pk4(vacc[2]), pk4(vacc[3]));  // s-tiles 2,3 (k' 32..63)
#pragma unroll
    for (int qt = 0; qt < 4; ++qt) {
      f32x4 g = {0.f, 0.f, 0.f, 0.f};
      g = MFMA(av0, pp[0][qt], g);
      g = MFMA(av1, pp[1][qt], g);
      int q = (qt << 4) + l15;
      if (q < S_LEN) *(f32x4*)&ob[q * DH + (dt << 4) + (lq << 2)] = g;
    }
    __builtin_amdgcn_s_setprio(0);
  }
}

extern "C" void kernel_launch(void* const* d_in, const int* in_sizes, int n_in,
                              void* d_out, int out_size, void* d_ws, size_t ws_size,
                              hipStream_t stream) {
  const float* x  = (const float*)d_in[0];
  const float* wq = (const float*)d_in[1];
  const float* wk = (const float*)d_in[2];
  const float* wv = (const float*)d_in[3];
  const float* wo = (const float*)d_in[4];
  // d_in[5] = mask (redundant with len_sequence; unused)
  const int* lens = (const int*)d_in[6];
  const int B = in_sizes[6];  // 4096

  float* out = (float*)d_out;
  float* attn = out + (size_t)B * S_LEN * DH;
  unsigned short* wbf = (unsigned short*)d_ws;  // 2 x 128 x 128 bf16 = 64 KB

  conv_all<<<128, 256, 0, stream>>>(wq, wk, wv, wo, wbf);
  tb_fused<<<B / 4, 256, 0, stream>>>(x, wbf, lens, out, attn);
}

// Round 19
// 91.883 us; speedup vs baseline: 1.1318x; 1.1318x over previous
//
#include <hip/hip_runtime.h>
#include <math.h>

#define S_LEN 56
#define DH 128

typedef float f32x4 __attribute__((ext_vector_type(4)));
typedef unsigned short u16x8 __attribute__((ext_vector_type(8)));
typedef unsigned short u16x4 __attribute__((ext_vector_type(4)));

__device__ __forceinline__ unsigned short f2bf(float f) {
  unsigned int u = __builtin_bit_cast(unsigned int, f);
  u += 0x7fffu + ((u >> 16) & 1u);  // RNE
  return (unsigned short)(u >> 16);
}
__device__ __forceinline__ unsigned short tobf(float f) {
  __bf16 h = (__bf16)f;
  return __builtin_bit_cast(unsigned short, h);
}
__device__ __forceinline__ u16x4 pk4(f32x4 v) {
  u16x4 r;
  r[0] = tobf(v[0]); r[1] = tobf(v[1]); r[2] = tobf(v[2]); r[3] = tobf(v[3]);
  return r;
}
__device__ __forceinline__ u16x8 pk8(f32x4 a, f32x4 b) {
  u16x8 r;
  r[0] = tobf(a[0]); r[1] = tobf(a[1]); r[2] = tobf(a[2]); r[3] = tobf(a[3]);
  r[4] = tobf(b[0]); r[5] = tobf(b[1]); r[6] = tobf(b[2]); r[7] = tobf(b[3]);
  return r;
}
__device__ __forceinline__ u16x8 cmb(u16x4 lo, u16x4 hi) {
  u16x8 r;
  r[0] = lo[0]; r[1] = lo[1]; r[2] = lo[2]; r[3] = lo[3];
  r[4] = hi[0]; r[5] = hi[1]; r[6] = hi[2]; r[7] = hi[3];
  return r;
}

template <typename V>
__device__ __forceinline__ auto mfma_sel(V a, V b, f32x4 c, int)
    -> decltype(__builtin_amdgcn_mfma_f32_16x16x32_bf16(a, b, c, 0, 0, 0)) {
  return __builtin_amdgcn_mfma_f32_16x16x32_bf16(a, b, c, 0, 0, 0);
}
template <typename V, typename E = __bf16>
__device__ __forceinline__ f32x4 mfma_sel(V a, V b, f32x4 c, long) {
  typedef E bfv __attribute__((ext_vector_type(8)));
  return __builtin_amdgcn_mfma_f32_16x16x32_bf16(
      __builtin_bit_cast(bfv, a), __builtin_bit_cast(bfv, b), c, 0, 0, 0);
}
__device__ __forceinline__ f32x4 MFMA(u16x8 a, u16x8 b, f32x4 c) {
  return mfma_sel(a, b, c, 0);
}

// One prep launch (r17-proven). Slot 0: A^T (A = Wq^T Wk). Slot 1: W2 = Wo·Wv.
__global__ void conv_all(const float* __restrict__ wq, const float* __restrict__ wk,
                         const float* __restrict__ wv, const float* __restrict__ wo,
                         unsigned short* __restrict__ o) {
  int bid = blockIdx.x;
  int i = (bid & 63) * 256 + threadIdx.x;  // 0..16383
  int r = i >> 7, c = i & 127;
  float s = 0.f;
  if (bid < 64) {
#pragma unroll 8
    for (int d = 0; d < DH; ++d) s += wq[d * DH + r] * wk[d * DH + c];
    o[c * DH + r] = f2bf(s);               // A^T[c][r] = A[r][c]
  } else {
#pragma unroll 8
    for (int d = 0; d < DH; ++d) s += wo[r * DH + d] * wv[d * DH + c];
    o[DH * DH + r * DH + c] = f2bf(s);     // W2[r][c], row-major
  }
}

// Cooperative 128x128-u16 weight stage: exactly 8 chunks = 32 KB (r13-fixed).
__device__ __forceinline__ void stageW(const unsigned short* __restrict__ src,
                                       unsigned short* wsh, int tid) {
  u16x8 v[8];
#pragma unroll
  for (int j = 0; j < 8; ++j)
    v[j] = *(const u16x8*)(src + ((j * 256 + tid) << 3));
#pragma unroll
  for (int j = 0; j < 8; ++j) {
    int row = j * 16 + (tid >> 4);
    int g = (tid & 15) ^ (row & 7);
    *(u16x8*)((char*)wsh + (row << 8) + (g << 4)) = v[j];
  }
}

// pi-fragment read from the swizzled LDS weight tile (r11-proven).
__device__ __forceinline__ u16x8 ldw(const unsigned short* wsh, int row,
                                     int kt, int lq) {
  int m = (row & 7) << 4;
  int p = (kt << 3) + lq;                     // 8-byte piece index
  int a0 = (row << 8) + (((p) << 3) ^ m);
  int a1 = (row << 8) + (((p + 4) << 3) ^ m);
  u16x4 lo = *(const u16x4*)((const char*)wsh + a0);
  u16x4 hi = *(const u16x4*)((const char*)wsh + a1);
  return cmb(lo, hi);
}

// r17 math verbatim; liveness dieted to fit 3 waves/SIMD (<=170 unified regs):
//  (1) E + softmax per qt-QUARTER (Ea[4] only; wf reads x4, LDS has headroom);
//  (2) wf0/wf1 sequential through one wf[4] buffer (yp = cmb(pk4,pk4) ==
//      pk8 bit-exactly);
//  (3) ya0 packed before ya1 computed;
//  (4) V' -> PV fused per dt-tile (r18 form, no av array).
// E-peak ~150-160, V'PV ~140. Single 32 KB LDS buffer (A^T then W2).
__global__ __launch_bounds__(256, 3) void tb_fused(
    const float* __restrict__ xg, const unsigned short* __restrict__ wbf,
    const int* __restrict__ lens, float* __restrict__ outg,
    float* __restrict__ attng) {
  __shared__ __align__(16) unsigned short wsh[DH * DH];  // 32 KB

  const int tid = threadIdx.x;
  const int w = tid >> 6;        // wave id -> sample
  const int lane = tid & 63;
  const int l15 = lane & 15;
  const int lq = lane >> 4;      // 0..3
  const int b = blockIdx.x * 4 + w;

  const int len = lens[b];
  const float* __restrict__ xb = xg + (size_t)b * (S_LEN * DH);

  // ---- stage A^T; x -> afp overlaps staging latency ----
  stageW(wbf, wsh, tid);
  u16x8 afp[4][4];
#pragma unroll
  for (int rt = 0; rt < 4; ++rt) {
    int row = (rt << 4) + l15;
#pragma unroll
    for (int kt = 0; kt < 4; ++kt) {
      u16x8 h = {0, 0, 0, 0, 0, 0, 0, 0};
      if (row < S_LEN) {
        const float* p = xb + row * DH + (kt << 5) + (lq << 2);
        f32x4 lo = *(const f32x4*)p;
        f32x4 hi = *(const f32x4*)(p + 16);
        h = pk8(lo, hi);
      }
      afp[rt][kt] = h;
    }
  }
  __syncthreads();  // B1: A^T staged

  const float sca = 0.08838834764831845f;  // 1/sqrt(128)
  const float slen = sqrtf((float)len);
  float* __restrict__ ab = attng + (size_t)b * (S_LEN * S_LEN);
  u16x8 pp[2][4];  // P'^T fragments, filled per qt

  // ---- E + softmax per qt-QUARTER (minimal accumulator liveness) ----
#pragma unroll
  for (int qt = 0; qt < 4; ++qt) {
    f32x4 Ea[4];  // [nt]; q = 16qt+l15, k' = 16nt+4lq+r (r9-proven map)
#pragma unroll
    for (int nt = 0; nt < 4; ++nt) Ea[nt] = f32x4{0.f, 0.f, 0.f, 0.f};

#pragma unroll
    for (int jp = 0; jp < 4; ++jp) {
      const int t0 = jp << 1, t1 = (jp << 1) | 1;
      u16x8 wf[4];
#pragma unroll
      for (int kt = 0; kt < 4; ++kt)
        wf[kt] = ldw(wsh, (t0 << 4) + l15, kt, lq);
      __builtin_amdgcn_s_setprio(1);
      f32x4 ya = {0.f, 0.f, 0.f, 0.f};
#pragma unroll
      for (int kt = 0; kt < 4; ++kt) ya = MFMA(wf[kt], afp[qt][kt], ya);
      u16x4 y0 = pk4(ya);
      __builtin_amdgcn_s_setprio(0);
#pragma unroll
      for (int kt = 0; kt < 4; ++kt)
        wf[kt] = ldw(wsh, (t1 << 4) + l15, kt, lq);
      __builtin_amdgcn_s_setprio(1);
      ya = f32x4{0.f, 0.f, 0.f, 0.f};
#pragma unroll
      for (int kt = 0; kt < 4; ++kt) ya = MFMA(wf[kt], afp[qt][kt], ya);
      u16x8 yp = cmb(y0, pk4(ya));  // == pk8(ya0, ya1) bit-exactly
#pragma unroll
      for (int nt = 0; nt < 4; ++nt)
        Ea[nt] = MFMA(afp[nt][jp], yp, Ea[nt]);
      __builtin_amdgcn_s_setprio(0);
    }

    // scale, mask, softmax, attn store, pp pack for this qt
#pragma unroll
    for (int nt = 0; nt < 4; ++nt)
#pragma unroll
      for (int r = 0; r < 4; ++r) {
        int kk = (nt << 4) + (lq << 2) + r;
        Ea[nt][r] = (kk < len) ? Ea[nt][r] * sca : -1e30f;
      }
    float m = -1e30f;
#pragma unroll
    for (int nt = 0; nt < 4; ++nt)
      m = fmaxf(m, fmaxf(fmaxf(Ea[nt][0], Ea[nt][1]),
                         fmaxf(Ea[nt][2], Ea[nt][3])));
    m = fmaxf(m, __shfl_xor(m, 16, 64));
    m = fmaxf(m, __shfl_xor(m, 32, 64));
    float s = 0.f;
#pragma unroll
    for (int nt = 0; nt < 4; ++nt)
#pragma unroll
      for (int r = 0; r < 4; ++r) {
        float p = __expf(Ea[nt][r] - m);
        Ea[nt][r] = p;
        s += p;
      }
    s += __shfl_xor(s, 16, 64);
    s += __shfl_xor(s, 32, 64);
    float iv = 1.f / s;
    float islen = iv * slen;

    int q = (qt << 4) + l15;
#pragma unroll
    for (int nt = 0; nt < 4; ++nt) {
      int cs = (nt << 4) + (lq << 2);
      f32x4 pv = Ea[nt] * iv;
      if (q < S_LEN && cs < S_LEN) *(f32x4*)&ab[q * S_LEN + cs] = pv;
    }
    pp[0][qt] = pk8(Ea[0] * islen, Ea[1] * islen);
    pp[1][qt] = pk8(Ea[2] * islen, Ea[3] * islen);
  }

  __syncthreads();                 // B2: all A^T reads done
  stageW(wbf + DH * DH, wsh, tid); // W2 -> LDS
  __syncthreads();                 // B3: W2 staged

  // ---- V' = x@W2^T fused with PV per dt-tile (no av array) ----
  float* __restrict__ ob = outg + (size_t)b * (S_LEN * DH);
#pragma unroll
  for (int dt = 0; dt < 8; ++dt) {
    u16x8 bfr[4];
#pragma unroll
    for (int kt = 0; kt < 4; ++kt)
      bfr[kt] = ldw(wsh, (dt << 4) + l15, kt, lq);
    __builtin_amdgcn_s_setprio(1);
    f32x4 vacc[4];
#pragma unroll
    for (int mt = 0; mt < 4; ++mt) vacc[mt] = f32x4{0.f, 0.f, 0.f, 0.f};
#pragma unroll
    for (int kt = 0; kt < 4; ++kt)
#pragma unroll
      for (int mt = 0; mt < 4; ++mt)
        vacc[mt] = MFMA(afp[mt][kt], bfr[kt], vacc[mt]);
    u16x8 av0 = cmb(pk4(vacc[0]), pk4(vacc[1]));  // s-tiles 0,1 (k' 0..31)
    u16x8 av1 = cmb(pk4(vacc[2]), pk4(vacc[3]));  // s-tiles 2,3 (k' 32..63)
#pragma unroll
    for (int qt = 0; qt < 4; ++qt) {
      f32x4 g = {0.f, 0.f, 0.f, 0.f};
      g = MFMA(av0, pp[0][qt], g);
      g = MFMA(av1, pp[1][qt], g);
      int q = (qt << 4) + l15;
      if (q < S_LEN) *(f32x4*)&ob[q * DH + (dt << 4) + (lq << 2)] = g;
    }
    __builtin_amdgcn_s_setprio(0);
  }
}

extern "C" void kernel_launch(void* const* d_in, const int* in_sizes, int n_in,
                              void* d_out, int out_size, void* d_ws, size_t ws_size,
                              hipStream_t stream) {
  const float* x  = (const float*)d_in[0];
  const float* wq = (const float*)d_in[1];
  const float* wk = (const float*)d_in[2];
  const float* wv = (const float*)d_in[3];
  const float* wo = (const float*)d_in[4];
  // d_in[5] = mask (redundant with len_sequence; unused)
  const int* lens = (const int*)d_in[6];
  const int B = in_sizes[6];  // 4096

  float* out = (float*)d_out;
  float* attn = out + (size_t)B * S_LEN * DH;
  unsigned short* wbf = (unsigned short*)d_ws;  // 2 x 128 x 128 bf16 = 64 KB

  conv_all<<<128, 256, 0, stream>>>(wq, wk, wv, wo, wbf);
  tb_fused<<<B / 4, 256, 0, stream>>>(x, wbf, lens, out, attn);
}

// Round 20
// 72.740 us; speedup vs baseline: 1.4297x; 1.2632x over previous
//
#include <hip/hip_runtime.h>
#include <math.h>

#define S_LEN 56
#define DH 128

typedef float f32x4 __attribute__((ext_vector_type(4)));
typedef unsigned short u16x8 __attribute__((ext_vector_type(8)));
typedef unsigned short u16x4 __attribute__((ext_vector_type(4)));

__device__ __forceinline__ unsigned short f2bf(float f) {
  unsigned int u = __builtin_bit_cast(unsigned int, f);
  u += 0x7fffu + ((u >> 16) & 1u);  // RNE
  return (unsigned short)(u >> 16);
}
__device__ __forceinline__ unsigned short tobf(float f) {
  __bf16 h = (__bf16)f;
  return __builtin_bit_cast(unsigned short, h);
}
__device__ __forceinline__ u16x4 pk4(f32x4 v) {
  u16x4 r;
  r[0] = tobf(v[0]); r[1] = tobf(v[1]); r[2] = tobf(v[2]); r[3] = tobf(v[3]);
  return r;
}
__device__ __forceinline__ u16x8 pk8(f32x4 a, f32x4 b) {
  u16x8 r;
  r[0] = tobf(a[0]); r[1] = tobf(a[1]); r[2] = tobf(a[2]); r[3] = tobf(a[3]);
  r[4] = tobf(b[0]); r[5] = tobf(b[1]); r[6] = tobf(b[2]); r[7] = tobf(b[3]);
  return r;
}
__device__ __forceinline__ u16x8 cmb(u16x4 lo, u16x4 hi) {
  u16x8 r;
  r[0] = lo[0]; r[1] = lo[1]; r[2] = lo[2]; r[3] = lo[3];
  r[4] = hi[0]; r[5] = hi[1]; r[6] = hi[2]; r[7] = hi[3];
  return r;
}

template <typename V>
__device__ __forceinline__ auto mfma_sel(V a, V b, f32x4 c, int)
    -> decltype(__builtin_amdgcn_mfma_f32_16x16x32_bf16(a, b, c, 0, 0, 0)) {
  return __builtin_amdgcn_mfma_f32_16x16x32_bf16(a, b, c, 0, 0, 0);
}
template <typename V, typename E = __bf16>
__device__ __forceinline__ f32x4 mfma_sel(V a, V b, f32x4 c, long) {
  typedef E bfv __attribute__((ext_vector_type(8)));
  return __builtin_amdgcn_mfma_f32_16x16x32_bf16(
      __builtin_bit_cast(bfv, a), __builtin_bit_cast(bfv, b), c, 0, 0, 0);
}
__device__ __forceinline__ f32x4 MFMA(u16x8 a, u16x8 b, f32x4 c) {
  return mfma_sel(a, b, c, 0);
}

// One prep launch (r17-proven). Slot 0: A^T (A = Wq^T Wk). Slot 1: W2 = Wo·Wv.
__global__ void conv_all(const float* __restrict__ wq, const float* __restrict__ wk,
                         const float* __restrict__ wv, const float* __restrict__ wo,
                         unsigned short* __restrict__ o) {
  int bid = blockIdx.x;
  int i = (bid & 63) * 256 + threadIdx.x;  // 0..16383
  int r = i >> 7, c = i & 127;
  float s = 0.f;
  if (bid < 64) {
#pragma unroll 8
    for (int d = 0; d < DH; ++d) s += wq[d * DH + r] * wk[d * DH + c];
    o[c * DH + r] = f2bf(s);               // A^T[c][r] = A[r][c]
  } else {
#pragma unroll 8
    for (int d = 0; d < DH; ++d) s += wo[r * DH + d] * wv[d * DH + c];
    o[DH * DH + r * DH + c] = f2bf(s);     // W2[r][c], row-major
  }
}

// Cooperative 128x128-u16 weight stage: exactly 8 chunks = 32 KB (r13-fixed).
__device__ __forceinline__ void stageW(const unsigned short* __restrict__ src,
                                       unsigned short* wsh, int tid) {
  u16x8 v[8];
#pragma unroll
  for (int j = 0; j < 8; ++j)
    v[j] = *(const u16x8*)(src + ((j * 256 + tid) << 3));
#pragma unroll
  for (int j = 0; j < 8; ++j) {
    int row = j * 16 + (tid >> 4);
    int g = (tid & 15) ^ (row & 7);
    *(u16x8*)((char*)wsh + (row << 8) + (g << 4)) = v[j];
  }
}

// pi-fragment read from the swizzled LDS weight tile (r11-proven).
__device__ __forceinline__ u16x8 ldw(const unsigned short* wsh, int row,
                                     int kt, int lq) {
  int m = (row & 7) << 4;
  int p = (kt << 3) + lq;                     // 8-byte piece index
  int a0 = (row << 8) + (((p) << 3) ^ m);
  int a1 = (row << 8) + (((p + 4) << 3) ^ m);
  u16x4 lo = *(const u16x4*)((const char*)wsh + a0);
  u16x4 hi = *(const u16x4*)((const char*)wsh + a1);
  return cmb(lo, hi);
}

// r17 champion structure (70.0 us) with two scheduler-level tweaks:
//  (1) ALL s_setprio removed (m190 measured it HURTING in some regimes;
//      never A/B'd here);
//  (2) V' phase software-pipelined: bfr for dt+1 prefetched from LDS before
//      dt's PV MFMAs (G7; +16 transient regs in the LOW-liveness phase).
// Math, layouts, staging, barrier count (1) all byte-identical to r17.
__global__ __launch_bounds__(256, 2) void tb_fused(
    const float* __restrict__ xg, const unsigned short* __restrict__ wbf,
    const int* __restrict__ lens, float* __restrict__ outg,
    float* __restrict__ attng) {
  __shared__ __align__(16) unsigned short wsh[2 * DH * DH];  // 64 KB, 2 bufs
  unsigned short* buf0 = wsh;             // A^T
  unsigned short* buf1 = wsh + DH * DH;   // W2

  const int tid = threadIdx.x;
  const int w = tid >> 6;        // wave id -> sample
  const int lane = tid & 63;
  const int l15 = lane & 15;
  const int lq = lane >> 4;      // 0..3
  const int b = blockIdx.x * 4 + w;

  const int len = lens[b];
  const float* __restrict__ xb = xg + (size_t)b * (S_LEN * DH);

  // ---- stage A^T -> buf0, W2 -> buf1 (16 loads in flight) ----
  stageW(wbf, buf0, tid);
  stageW(wbf + DH * DH, buf1, tid);

  // ---- x -> registers afp[rt][kt], pi map (overlaps staging latency) ----
  u16x8 afp[4][4];
#pragma unroll
  for (int rt = 0; rt < 4; ++rt) {
    int row = (rt << 4) + l15;
#pragma unroll
    for (int kt = 0; kt < 4; ++kt) {
      u16x8 h = {0, 0, 0, 0, 0, 0, 0, 0};
      if (row < S_LEN) {
        const float* p = xb + row * DH + (kt << 5) + (lq << 2);
        f32x4 lo = *(const f32x4*)p;
        f32x4 hi = *(const f32x4*)(p + 16);
        h = pk8(lo, hi);
      }
      afp[rt][kt] = h;
    }
  }
  __syncthreads();  // B1 (the ONLY barrier): A^T + W2 staged

  // ---- E = x A x^T: per jp, Y-pair (d'-chunk) then fold into Ea ----
  f32x4 Ea[4][4];  // [qt][nt]; lane: q=16qt+l15, k'=16nt+4lq+r (r9-proven)
#pragma unroll
  for (int qt = 0; qt < 4; ++qt)
#pragma unroll
    for (int nt = 0; nt < 4; ++nt) Ea[qt][nt] = f32x4{0.f, 0.f, 0.f, 0.f};

#pragma unroll
  for (int jp = 0; jp < 4; ++jp) {
    const int t0 = jp << 1, t1 = (jp << 1) | 1;
    u16x8 wf0[4], wf1[4];
#pragma unroll
    for (int kt = 0; kt < 4; ++kt) {
      wf0[kt] = ldw(buf0, (t0 << 4) + l15, kt, lq);
      wf1[kt] = ldw(buf0, (t1 << 4) + l15, kt, lq);
    }
    f32x4 ya0[4], ya1[4];
#pragma unroll
    for (int qt = 0; qt < 4; ++qt) {
      ya0[qt] = f32x4{0.f, 0.f, 0.f, 0.f};
      ya1[qt] = f32x4{0.f, 0.f, 0.f, 0.f};
    }
#pragma unroll
    for (int kt = 0; kt < 4; ++kt)
#pragma unroll
      for (int qt = 0; qt < 4; ++qt) {
        ya0[qt] = MFMA(wf0[kt], afp[qt][kt], ya0[qt]);
        ya1[qt] = MFMA(wf1[kt], afp[qt][kt], ya1[qt]);
      }
    u16x8 yp[4];
#pragma unroll
    for (int qt = 0; qt < 4; ++qt) yp[qt] = pk8(ya0[qt], ya1[qt]);
#pragma unroll
    for (int nt = 0; nt < 4; ++nt)
#pragma unroll
      for (int qt = 0; qt < 4; ++qt)
        Ea[qt][nt] = MFMA(afp[nt][jp], yp[qt], Ea[qt][nt]);
  }

  // ---- scale, mask, softmax per q-tile ----
  const float sca = 0.08838834764831845f;  // 1/sqrt(128)
  float inv_[4];
#pragma unroll
  for (int qt = 0; qt < 4; ++qt) {
#pragma unroll
    for (int nt = 0; nt < 4; ++nt)
#pragma unroll
      for (int r = 0; r < 4; ++r) {
        int kk = (nt << 4) + (lq << 2) + r;
        Ea[qt][nt][r] = (kk < len) ? Ea[qt][nt][r] * sca : -1e30f;
      }
    float m = -1e30f;
#pragma unroll
    for (int nt = 0; nt < 4; ++nt)
      m = fmaxf(m, fmaxf(fmaxf(Ea[qt][nt][0], Ea[qt][nt][1]),
                         fmaxf(Ea[qt][nt][2], Ea[qt][nt][3])));
    m = fmaxf(m, __shfl_xor(m, 16, 64));
    m = fmaxf(m, __shfl_xor(m, 32, 64));
    float s = 0.f;
#pragma unroll
    for (int nt = 0; nt < 4; ++nt)
#pragma unroll
      for (int r = 0; r < 4; ++r) {
        float p = __expf(Ea[qt][nt][r] - m);
        Ea[qt][nt][r] = p;
        s += p;
      }
    s += __shfl_xor(s, 16, 64);
    s += __shfl_xor(s, 32, 64);
    inv_[qt] = 1.f / s;
  }

  // ---- attn store (f32x4) + P^T pack pp[c][qt]; Ea dies here ----
  const float slen = sqrtf((float)len);
  float* __restrict__ ab = attng + (size_t)b * (S_LEN * S_LEN);
  u16x8 pp[2][4];
#pragma unroll
  for (int qt = 0; qt < 4; ++qt) {
    int q = (qt << 4) + l15;
    float iv = inv_[qt];
    float islen = iv * slen;
#pragma unroll
    for (int nt = 0; nt < 4; ++nt) {
      int cs = (nt << 4) + (lq << 2);
      f32x4 pv = Ea[qt][nt] * iv;
      if (q < S_LEN && cs < S_LEN) *(f32x4*)&ab[q * S_LEN + cs] = pv;
    }
    pp[0][qt] = pk8(Ea[qt][0] * islen, Ea[qt][1] * islen);
    pp[1][qt] = pk8(Ea[qt][2] * islen, Ea[qt][3] * islen);
  }

  // ---- V' = x @ W2^T fused with PV per dt-tile, bfr double-buffered ----
  float* __restrict__ ob = outg + (size_t)b * (S_LEN * DH);
  u16x8 bfr[4];
#pragma unroll
  for (int kt = 0; kt < 4; ++kt)
    bfr[kt] = ldw(buf1, 0 + l15, kt, lq);       // preload dt = 0
#pragma unroll
  for (int dt = 0; dt < 8; ++dt) {
    u16x8 bfn[4];
    if (dt < 7) {
#pragma unroll
      for (int kt = 0; kt < 4; ++kt)
        bfn[kt] = ldw(buf1, ((dt + 1) << 4) + l15, kt, lq);  // prefetch dt+1
    }
    f32x4 vacc[4];
#pragma unroll
    for (int mt = 0; mt < 4; ++mt) vacc[mt] = f32x4{0.f, 0.f, 0.f, 0.f};
#pragma unroll
    for (int kt = 0; kt < 4; ++kt)
#pragma unroll
      for (int mt = 0; mt < 4; ++mt)
        vacc[mt] = MFMA(afp[mt][kt], bfr[kt], vacc[mt]);
    u16x8 av0 = cmb(pk4(vacc[0]), pk4(vacc[1]));  // s-tiles 0,1 (k' 0..31)
    u16x8 av1 = cmb(pk4(vacc[2]), pk4(vacc[3]));  // s-tiles 2,3 (k' 32..63)
#pragma unroll
    for (int qt = 0; qt < 4; ++qt) {
      f32x4 g = {0.f, 0.f, 0.f, 0.f};
      g = MFMA(av0, pp[0][qt], g);
      g = MFMA(av1, pp[1][qt], g);
      int q = (qt << 4) + l15;
      if (q < S_LEN) *(f32x4*)&ob[q * DH + (dt << 4) + (lq << 2)] = g;
    }
    if (dt < 7) {
#pragma unroll
      for (int kt = 0; kt < 4; ++kt) bfr[kt] = bfn[kt];  // renamed away
    }
  }
}

extern "C" void kernel_launch(void* const* d_in, const int* in_sizes, int n_in,
                              void* d_out, int out_size, void* d_ws, size_t ws_size,
                              hipStream_t stream) {
  const float* x  = (const float*)d_in[0];
  const float* wq = (const float*)d_in[1];
  const float* wk = (const float*)d_in[2];
  const float* wv = (const float*)d_in[3];
  const float* wo = (const float*)d_in[4];
  // d_in[5] = mask (redundant with len_sequence; unused)
  const int* lens = (const int*)d_in[6];
  const int B = in_sizes[6];  // 4096

  float* out = (float*)d_out;
  float* attn = out + (size_t)B * S_LEN * DH;
  unsigned short* wbf = (unsigned short*)d_ws;  // 2 x 128 x 128 bf16 = 64 KB

  conv_all<<<128, 256, 0, stream>>>(wq, wk, wv, wo, wbf);
  tb_fused<<<B / 4, 256, 0, stream>>>(x, wbf, lens, out, attn);
}